// Round 1
// baseline (609.879 us; speedup 1.0000x reference)
//
#include <hip/hip_runtime.h>
#include <math.h>

#define NB 4
#define NT 4096
#define NC 512
#define NH 64
#define ROWS 4          // query rows per block (1 per wave)
#define KTILE 64        // keys per LDS tile
#define LDK 68          // padded LDS row stride (floats): 272B = 17*16B, float4-aligned

// ---------------- Kernel 1: fused QKV projection ----------------
// One 64-thread block per token row. x-row in LDS (broadcast reads),
// W reads coalesced across lanes. q is pre-scaled by 1/sqrt(C).
__global__ __launch_bounds__(64) void qkv_proj(
    const float* __restrict__ x,   // [B*T, C]
    const float* __restrict__ Wk,  // [C, H]
    const float* __restrict__ Wq,
    const float* __restrict__ Wv,
    float* __restrict__ q,         // [B*T, H]
    float* __restrict__ k,
    float* __restrict__ v)
{
    __shared__ float xrow[NC];
    const int row = blockIdx.x;
    const int h = threadIdx.x;
    const float* xr = x + (size_t)row * NC;
    // 512 floats = 128 float4; 64 threads -> 2 float4 each, coalesced
    #pragma unroll
    for (int i = 0; i < NC/4/64; ++i)
        reinterpret_cast<float4*>(xrow)[h + i*64] =
            reinterpret_cast<const float4*>(xr)[h + i*64];
    __syncthreads();

    float aq = 0.f, ak = 0.f, av = 0.f;
    #pragma unroll 4
    for (int c = 0; c < NC; ++c) {
        float xv = xrow[c];
        aq = fmaf(xv, Wq[c*NH + h], aq);
        ak = fmaf(xv, Wk[c*NH + h], ak);
        av = fmaf(xv, Wv[c*NH + h], av);
    }
    const float scale = 0.044194173824159216f; // 1/sqrt(512)
    q[(size_t)row*NH + h] = aq * scale;
    k[(size_t)row*NH + h] = ak;
    v[(size_t)row*NH + h] = av;
}

// ---------------- Kernel 2: flash attention (fp32 VALU) ----------------
// 4 query rows per block (one per wave). K/V staged in LDS tiles of 64 keys,
// shared by all 4 waves. Each lane owns one key per tile; per-lane online
// softmax (m, l, o[64]); cross-lane merge at the end via shfl butterflies.
__global__ __launch_bounds__(256) void attn_fwd(
    const float* __restrict__ q,   // [B*T, H], pre-scaled
    const float* __restrict__ k,
    const float* __restrict__ v,
    float* __restrict__ out)       // [B*T, H]
{
    __shared__ float k_lds[KTILE][LDK];
    __shared__ float v_lds[KTILE][LDK];
    __shared__ float q_lds[ROWS][NH];

    const int tid  = threadIdx.x;
    const int wave = tid >> 6;
    const int lane = tid & 63;
    const int blocksPerBatch = NT / ROWS;
    const int b  = blockIdx.x / blocksPerBatch;
    const int t0 = (blockIdx.x % blocksPerBatch) * ROWS;
    const int t  = t0 + wave;                  // this wave's query row
    const size_t base = (size_t)b * NT * NH;

    q_lds[wave][lane] = q[base + (size_t)t * NH + lane];
    __syncthreads();

    // hoist q into registers (16 float4)
    float4 qv[NH/4];
    #pragma unroll
    for (int i = 0; i < NH/4; ++i)
        qv[i] = *reinterpret_cast<const float4*>(&q_lds[wave][4*i]);

    float m = -INFINITY, l = 0.f;
    float o[NH];
    #pragma unroll
    for (int hh = 0; hh < NH; ++hh) o[hh] = 0.f;

    const int t_max = t0 + ROWS - 1;
    for (int s0 = 0; s0 <= t_max; s0 += KTILE) {
        __syncthreads();  // previous tile fully consumed
        // stage K/V tile: 64 rows x 64 floats each = 1024 float4 per array;
        // 256 threads -> 4 float4 each, coalesced global reads
        #pragma unroll
        for (int i = 0; i < 4; ++i) {
            int idx = tid + i*256;
            int r  = idx >> 4;
            int cq = idx & 15;
            const float* krow = k + base + (size_t)(s0 + r) * NH;
            const float* vrow = v + base + (size_t)(s0 + r) * NH;
            float4 kk = reinterpret_cast<const float4*>(krow)[cq];
            float4 vv = reinterpret_cast<const float4*>(vrow)[cq];
            *reinterpret_cast<float4*>(&k_lds[r][cq*4]) = kk;
            *reinterpret_cast<float4*>(&v_lds[r][cq*4]) = vv;
        }
        __syncthreads();

        const int s = s0 + lane;   // this lane's key
        if (s <= t) {
            float dot = 0.f;
            #pragma unroll
            for (int i = 0; i < NH/4; ++i) {
                float4 kk = *reinterpret_cast<const float4*>(&k_lds[lane][4*i]);
                dot = fmaf(qv[i].x, kk.x, dot);
                dot = fmaf(qv[i].y, kk.y, dot);
                dot = fmaf(qv[i].z, kk.z, dot);
                dot = fmaf(qv[i].w, kk.w, dot);
            }
            float mn   = fmaxf(m, dot);
            float corr = __expf(m - mn);    // m=-inf first time -> 0
            float p    = __expf(dot - mn);
            l = l * corr + p;
            m = mn;
            #pragma unroll
            for (int i = 0; i < NH/4; ++i) {
                float4 vv = *reinterpret_cast<const float4*>(&v_lds[lane][4*i]);
                o[4*i+0] = fmaf(o[4*i+0], corr, p * vv.x);
                o[4*i+1] = fmaf(o[4*i+1], corr, p * vv.y);
                o[4*i+2] = fmaf(o[4*i+2], corr, p * vv.z);
                o[4*i+3] = fmaf(o[4*i+3], corr, p * vv.w);
            }
        }
    }

    // ---- cross-lane merge of 64 per-lane partial softmaxes ----
    float M = m;
    #pragma unroll
    for (int off = 32; off > 0; off >>= 1) M = fmaxf(M, __shfl_xor(M, off));
    float w = (m == -INFINITY) ? 0.f : __expf(m - M);
    float denom = w * l;
    #pragma unroll
    for (int off = 32; off > 0; off >>= 1) denom += __shfl_xor(denom, off);

    float num = 0.f;
    #pragma unroll
    for (int hh = 0; hh < NH; ++hh) {
        float val = w * o[hh];
        #pragma unroll
        for (int off = 32; off > 0; off >>= 1) val += __shfl_xor(val, off);
        if (lane == hh) num = val;   // lane hh keeps output dim hh
    }
    out[base + (size_t)t * NH + lane] = num / denom;
}

extern "C" void kernel_launch(void* const* d_in, const int* in_sizes, int n_in,
                              void* d_out, int out_size, void* d_ws, size_t ws_size,
                              hipStream_t stream) {
    const float* x  = (const float*)d_in[0];
    const float* Wk = (const float*)d_in[1];
    const float* Wq = (const float*)d_in[2];
    const float* Wv = (const float*)d_in[3];
    float* out = (float*)d_out;

    const size_t n = (size_t)NB * NT * NH;   // 1,048,576 elements
    float* qb = (float*)d_ws;
    float* kb = qb + n;
    float* vb = kb + n;                       // total 12 MB of d_ws

    qkv_proj<<<NB*NT, 64, 0, stream>>>(x, Wk, Wq, Wv, qb, kb, vb);
    attn_fwd<<<NB*(NT/ROWS), 256, 0, stream>>>(qb, kb, vb, out);
}

// Round 2
// 177.879 us; speedup vs baseline: 3.4286x; 3.4286x over previous
//
#include <hip/hip_runtime.h>
#include <hip/hip_bf16.h>
#include <math.h>

#define NB 4
#define NT 4096
#define NC 512
#define NH 64
#define QBLK 64
#define KVBLK 64
#define LDK 72   // padded LDS row stride in bf16 elems (144 B) -> kills D=64 bank conflicts

typedef __attribute__((ext_vector_type(8))) short bf16x8;
typedef __attribute__((ext_vector_type(4))) float f32x4;

__device__ inline unsigned short f2bf(float f) {
    __hip_bfloat16 h = __float2bfloat16(f);
    return *reinterpret_cast<unsigned short*>(&h);
}

// ---------------- Kernel 1: fused QKV projection (fp32 math, bf16 out) ----------------
// 32 token rows per 256-thread block; x rows staged in LDS (broadcast reads);
// W reads coalesced and amortized over 32 rows (32x less L2 traffic than 1-row blocks).
// q is pre-scaled by 1/sqrt(C).
__global__ __launch_bounds__(256) void qkv_proj(
    const float* __restrict__ x,
    const float* __restrict__ Wk,
    const float* __restrict__ Wq,
    const float* __restrict__ Wv,
    unsigned short* __restrict__ q,
    unsigned short* __restrict__ k,
    unsigned short* __restrict__ v)
{
    __shared__ float xs[32][NC];        // 64 KB
    const int tid = threadIdx.x;
    const size_t r0 = (size_t)blockIdx.x * 32;

    const float4* xg = reinterpret_cast<const float4*>(x + r0 * NC);
    float4* xl = reinterpret_cast<float4*>(&xs[0][0]);
    #pragma unroll
    for (int i = 0; i < 16; ++i) xl[tid + i*256] = xg[tid + i*256];
    __syncthreads();

    const int h = tid & 63;
    const int w = tid >> 6;             // wave handles rows 8w..8w+7
    float aq[8], ak[8], av[8];
    #pragma unroll
    for (int r = 0; r < 8; ++r) { aq[r] = 0.f; ak[r] = 0.f; av[r] = 0.f; }

    const float* wqp = Wq + h;
    const float* wkp = Wk + h;
    const float* wvp = Wv + h;
    #pragma unroll 2
    for (int c = 0; c < NC; ++c) {
        float fq = wqp[c*NH], fk = wkp[c*NH], fv = wvp[c*NH];
        #pragma unroll
        for (int r = 0; r < 8; ++r) {
            float xv = xs[8*w + r][c];
            aq[r] = fmaf(xv, fq, aq[r]);
            ak[r] = fmaf(xv, fk, ak[r]);
            av[r] = fmaf(xv, fv, av[r]);
        }
    }
    const float scale = 0.044194173824159216f; // 1/sqrt(512)
    #pragma unroll
    for (int r = 0; r < 8; ++r) {
        size_t row = r0 + 8*w + r;
        q[row*NH + h] = f2bf(aq[r] * scale);
        k[row*NH + h] = f2bf(ak[r]);
        v[row*NH + h] = f2bf(av[r]);
    }
}

// ---------------- Kernel 2: MFMA flash attention ----------------
// 64 q-rows per 256-thread block; wave w owns rows [q0+16w, +16).
// Swapped compute: S^T = K·Q^T (lane owns one q-column -> softmax reduce = 2 shfl),
// then O^T = V^T·P^T with V transposed at staging and P^T via per-wave LDS roundtrip.
__global__ __launch_bounds__(256) void attn_fwd(
    const unsigned short* __restrict__ qg,
    const unsigned short* __restrict__ kg,
    const unsigned short* __restrict__ vg,
    float* __restrict__ out)
{
    __shared__ unsigned short k_lds[KVBLK][LDK];   // K tile, row-major [kv][c]
    __shared__ unsigned short vt_lds[NH][LDK];     // V^T tile [d][kv]
    __shared__ unsigned short p_lds[4][16][LDK];   // per-wave P [q][kv]

    const int tid  = threadIdx.x;
    const int w    = tid >> 6;
    const int lane = tid & 63;
    const int l15  = lane & 15;
    const int g    = lane >> 4;

    const int b  = blockIdx.x & 3;
    const int qt = (NT/QBLK - 1) - (blockIdx.x >> 2);  // heavy tiles first
    const int q0 = qt * QBLK;
    const size_t base = (size_t)b * NT * NH;
    const int qrow = q0 + 16*w + l15;                  // this lane's q column

    // Q fragment (B-operand of S^T): lane holds Q[qrow][8g + j (+32)]
    bf16x8 qf0, qf1;
    {
        const unsigned short* qp = qg + base + (size_t)qrow * NH + 8*g;
        qf0 = *reinterpret_cast<const bf16x8*>(qp);
        qf1 = *reinterpret_cast<const bf16x8*>(qp + 32);
    }

    f32x4 ot[4];   // O^T tiles: lane holds O^T[16dt+4g+r][qrow]
    #pragma unroll
    for (int i = 0; i < 4; ++i) ot[i] = (f32x4){0.f, 0.f, 0.f, 0.f};
    float m = -INFINITY, lsum = 0.f;

    const int nT  = qt + 1;
    const int qhi = q0 + 16*w + 15;

    for (int it = 0; it < nT; ++it) {
        const int s0 = it * KVBLK;
        __syncthreads();   // previous tile consumed
        // ---- stage K tile (8 KB, vectorized, coalesced) ----
        #pragma unroll
        for (int i = 0; i < 2; ++i) {
            int idx = tid + i*256;
            int row = idx >> 3, c8 = idx & 7;
            bf16x8 kk8 = *reinterpret_cast<const bf16x8*>(
                kg + base + (size_t)(s0 + row) * NH + c8*8);
            *reinterpret_cast<bf16x8*>(&k_lds[row][c8*8]) = kk8;
        }
        // ---- stage V^T tile (coalesced u16 global reads, vector LDS writes) ----
        {
            int d = tid & 63, kq = tid >> 6;
            unsigned short tmp[16];
            #pragma unroll
            for (int i = 0; i < 16; ++i)
                tmp[i] = vg[base + (size_t)(s0 + kq*16 + i) * NH + d];
            *reinterpret_cast<bf16x8*>(&vt_lds[d][kq*16])     = *reinterpret_cast<bf16x8*>(&tmp[0]);
            *reinterpret_cast<bf16x8*>(&vt_lds[d][kq*16 + 8]) = *reinterpret_cast<bf16x8*>(&tmp[8]);
        }
        __syncthreads();
        if (s0 > qhi) continue;   // tile fully above diagonal for this wave

        // ---- S^T = K · Q^T : 4 kv-subtiles x (K=64 -> 2 chained MFMAs) ----
        f32x4 s[4];
        #pragma unroll
        for (int t = 0; t < 4; ++t) {
            bf16x8 ka = *reinterpret_cast<const bf16x8*>(&k_lds[16*t + l15][8*g]);
            bf16x8 kb = *reinterpret_cast<const bf16x8*>(&k_lds[16*t + l15][8*g + 32]);
            s[t] = __builtin_amdgcn_mfma_f32_16x16x32_bf16(ka, qf0, (f32x4){0.f,0.f,0.f,0.f}, 0, 0, 0);
            s[t] = __builtin_amdgcn_mfma_f32_16x16x32_bf16(kb, qf1, s[t], 0, 0, 0);
        }

        // ---- causal mask: lane holds S^T[kv = s0+16t+4g+r][qrow] ----
        const int kvb = s0 + 4*g;
        #pragma unroll
        for (int t = 0; t < 4; ++t)
            #pragma unroll
            for (int r = 0; r < 4; ++r)
                if (kvb + 16*t + r > qrow) s[t][r] = -INFINITY;

        // ---- online softmax per q-column (reduce over g: 2 shfls) ----
        float pm = -INFINITY;
        #pragma unroll
        for (int t = 0; t < 4; ++t)
            #pragma unroll
            for (int r = 0; r < 4; ++r) pm = fmaxf(pm, s[t][r]);
        pm = fmaxf(pm, __shfl_xor(pm, 16));
        pm = fmaxf(pm, __shfl_xor(pm, 32));

        float mn   = fmaxf(m, pm);
        float corr = __expf(m - mn);   // m=-inf first iter -> 0
        m = mn;

        float ps = 0.f;
        #pragma unroll
        for (int t = 0; t < 4; ++t)
            #pragma unroll
            for (int r = 0; r < 4; ++r) {
                float pv = __expf(s[t][r] - mn);
                s[t][r] = pv;
                ps += pv;
            }

        // write P^T to per-wave LDS as P[q][kv] (pairs packed to u32)
        #pragma unroll
        for (int t = 0; t < 4; ++t) {
            unsigned int w0 = (unsigned int)f2bf(s[t][0]) | ((unsigned int)f2bf(s[t][1]) << 16);
            unsigned int w1 = (unsigned int)f2bf(s[t][2]) | ((unsigned int)f2bf(s[t][3]) << 16);
            *reinterpret_cast<unsigned int*>(&p_lds[w][l15][16*t + 4*g])     = w0;
            *reinterpret_cast<unsigned int*>(&p_lds[w][l15][16*t + 4*g + 2]) = w1;
        }

        ps += __shfl_xor(ps, 16);
        ps += __shfl_xor(ps, 32);
        lsum = lsum * corr + ps;

        #pragma unroll
        for (int dt = 0; dt < 4; ++dt)
            #pragma unroll
            for (int e = 0; e < 4; ++e) ot[dt][e] *= corr;

        // ---- O^T += V^T · P^T ----
        #pragma unroll
        for (int kk = 0; kk < 2; ++kk) {
            bf16x8 pf = *reinterpret_cast<const bf16x8*>(&p_lds[w][l15][8*g + 32*kk]);
            #pragma unroll
            for (int dt = 0; dt < 4; ++dt) {
                bf16x8 vf = *reinterpret_cast<const bf16x8*>(&vt_lds[16*dt + l15][8*g + 32*kk]);
                ot[dt] = __builtin_amdgcn_mfma_f32_16x16x32_bf16(vf, pf, ot[dt], 0, 0, 0);
            }
        }
    }

    // ---- epilogue: out[qrow][d] = O^T[d][qrow] / lsum ----
    const float inv = 1.f / lsum;
    float* orow = out + base + (size_t)qrow * NH;
    #pragma unroll
    for (int dt = 0; dt < 4; ++dt) {
        f32x4 o4;
        #pragma unroll
        for (int r = 0; r < 4; ++r) o4[r] = ot[dt][r] * inv;
        *reinterpret_cast<f32x4*>(&orow[16*dt + 4*g]) = o4;
    }
}

extern "C" void kernel_launch(void* const* d_in, const int* in_sizes, int n_in,
                              void* d_out, int out_size, void* d_ws, size_t ws_size,
                              hipStream_t stream) {
    const float* x  = (const float*)d_in[0];
    const float* Wk = (const float*)d_in[1];
    const float* Wq = (const float*)d_in[2];
    const float* Wv = (const float*)d_in[3];
    float* out = (float*)d_out;

    const size_t n = (size_t)NB * NT * NH;           // 1,048,576 elems
    unsigned short* qb = (unsigned short*)d_ws;      // 2 MB each, 6 MB total
    unsigned short* kb = qb + n;
    unsigned short* vb = kb + n;

    qkv_proj<<<NB*NT/32, 256, 0, stream>>>(x, Wk, Wq, Wv, qb, kb, vb);
    attn_fwd<<<NB*(NT/QBLK), 256, 0, stream>>>(qb, kb, vb, out);
}

// Round 3
// 123.794 us; speedup vs baseline: 4.9266x; 1.4369x over previous
//
#include <hip/hip_runtime.h>
#include <hip/hip_bf16.h>
#include <math.h>

#define NB 4
#define NT 4096
#define NC 512
#define NH 64
#define QBLK 64
#define KVBLK 64
#define LDK 72   // padded LDS row stride in bf16 elems (144 B)

typedef __attribute__((ext_vector_type(8))) short bf16x8;
typedef __attribute__((ext_vector_type(4))) float f32x4;

__device__ inline unsigned short f2bf(float f) {
    __hip_bfloat16 h = __float2bfloat16(f);
    return *reinterpret_cast<unsigned short*>(&h);
}

// ---------------- Kernel 0: pack W^T bf16 [192][512], Wq pre-scaled ----------------
__global__ __launch_bounds__(256) void wconv(
    const float* __restrict__ Wk, const float* __restrict__ Wq,
    const float* __restrict__ Wv, unsigned short* __restrict__ Wt)
{
    int idx = blockIdx.x * 256 + threadIdx.x;   // 98304 = 512*192
    int n = idx % 192, c = idx / 192;
    int sel = n >> 6, h = n & 63;
    const float* W = (sel == 0) ? Wq : (sel == 1) ? Wk : Wv;
    float val = W[c * NH + h];
    if (sel == 0) val *= 0.044194173824159216f;  // 1/sqrt(512)
    Wt[n * NC + c] = f2bf(val);
}

// ---------------- Kernel 1: QKV projection as MFMA GEMM ----------------
// [16384,512] x [512,192] -> q|k|v bf16. BM=64, BN=192, BK=64; 4 waves,
// each wave owns a 64x48 strip (4x3 fragments of 16x16). fp32->bf16 fused
// into A staging; B is pre-packed Wt (row-major [n][c] = B^T, so frag reads
// are contiguous ds_read_b128).
__global__ __launch_bounds__(256) void qkv_gemm(
    const float* __restrict__ x, const unsigned short* __restrict__ Wt,
    unsigned short* __restrict__ q, unsigned short* __restrict__ k,
    unsigned short* __restrict__ v)
{
    __shared__ unsigned short xa[64][LDK];    // A tile  (9.2 KB)
    __shared__ unsigned short wb[192][LDK];   // B tile (27.6 KB)

    const int tid = threadIdx.x;
    const int w = tid >> 6, lane = tid & 63, l15 = lane & 15, g = lane >> 4;
    const size_t r0 = (size_t)blockIdx.x * 64;

    f32x4 acc[4][3];
    #pragma unroll
    for (int mt = 0; mt < 4; ++mt)
        #pragma unroll
        for (int nt = 0; nt < 3; ++nt) acc[mt][nt] = (f32x4){0.f,0.f,0.f,0.f};

    for (int c0 = 0; c0 < NC; c0 += 64) {
        __syncthreads();   // previous tile consumed
        // stage A: 64x64 fp32 -> bf16 (512 chunks of 8)
        #pragma unroll
        for (int i = 0; i < 2; ++i) {
            int idx = tid + 256*i;
            int row = idx >> 3, f8 = idx & 7;
            const float* xp = x + (r0 + row) * NC + c0 + f8*8;
            float4 x0 = *reinterpret_cast<const float4*>(xp);
            float4 x1 = *reinterpret_cast<const float4*>(xp + 4);
            bf16x8 a8;
            a8[0]=f2bf(x0.x); a8[1]=f2bf(x0.y); a8[2]=f2bf(x0.z); a8[3]=f2bf(x0.w);
            a8[4]=f2bf(x1.x); a8[5]=f2bf(x1.y); a8[6]=f2bf(x1.z); a8[7]=f2bf(x1.w);
            *reinterpret_cast<bf16x8*>(&xa[row][f8*8]) = a8;
        }
        // stage B: 192x64 bf16 (1536 chunks of 8)
        #pragma unroll
        for (int i = 0; i < 6; ++i) {
            int idx = tid + 256*i;
            int row = idx >> 3, f8 = idx & 7;
            bf16x8 w8 = *reinterpret_cast<const bf16x8*>(Wt + (size_t)row * NC + c0 + f8*8);
            *reinterpret_cast<bf16x8*>(&wb[row][f8*8]) = w8;
        }
        __syncthreads();

        #pragma unroll
        for (int kk = 0; kk < 2; ++kk) {
            bf16x8 a[4], bfr[3];
            #pragma unroll
            for (int mt = 0; mt < 4; ++mt)
                a[mt] = *reinterpret_cast<const bf16x8*>(&xa[16*mt + l15][32*kk + 8*g]);
            #pragma unroll
            for (int nt = 0; nt < 3; ++nt)
                bfr[nt] = *reinterpret_cast<const bf16x8*>(&wb[48*w + 16*nt + l15][32*kk + 8*g]);
            __builtin_amdgcn_s_setprio(1);
            #pragma unroll
            for (int mt = 0; mt < 4; ++mt)
                #pragma unroll
                for (int nt = 0; nt < 3; ++nt)
                    acc[mt][nt] = __builtin_amdgcn_mfma_f32_16x16x32_bf16(a[mt], bfr[nt], acc[mt][nt], 0, 0, 0);
            __builtin_amdgcn_s_setprio(0);
        }
    }

    // epilogue: D[m][n]: m = 16mt+4g+r, n = 48w+16nt+l15; sel uniform per (w,nt)
    #pragma unroll
    for (int mt = 0; mt < 4; ++mt)
        #pragma unroll
        for (int nt = 0; nt < 3; ++nt) {
            int ncol = 48*w + 16*nt + l15;
            int sel = ncol >> 6, h = ncol & 63;
            unsigned short* dst = (sel == 0) ? q : (sel == 1) ? k : v;
            #pragma unroll
            for (int r = 0; r < 4; ++r)
                dst[(r0 + 16*mt + 4*g + r) * NH + h] = f2bf(acc[mt][nt][r]);
        }
}

// ---------------- Kernel 2: MFMA flash attention, prefetch double-buffer ----------------
// 64 q-rows/block, wave w owns 16 rows. S^T = K·Q^T (lane owns one q-col,
// softmax reduce = 2 shfl); O^T = V^T·P^T. K/V for tile t+1 are loaded into
// registers right after the barrier (in flight during tile t's compute);
// one barrier per tile-iter (write(b)@it+2 vs read(b)@it separated by barrier@it+1).
__global__ __launch_bounds__(256) void attn_fwd(
    const unsigned short* __restrict__ qg,
    const unsigned short* __restrict__ kg,
    const unsigned short* __restrict__ vg,
    float* __restrict__ out)
{
    __shared__ unsigned short k_lds[2][KVBLK][LDK];   // 18.4 KB
    __shared__ unsigned short vt_lds[2][NH][LDK];     // 18.4 KB
    __shared__ unsigned short p_lds[4][16][LDK];      //  9.2 KB

    const int tid  = threadIdx.x;
    const int w    = tid >> 6;
    const int lane = tid & 63;
    const int l15  = lane & 15;
    const int g    = lane >> 4;

    const int b  = blockIdx.x & 3;
    const int qt = (NT/QBLK - 1) - (blockIdx.x >> 2);  // heavy tiles first
    const int q0 = qt * QBLK;
    const size_t base = (size_t)b * NT * NH;
    const int qrow = q0 + 16*w + l15;

    bf16x8 qf0, qf1;
    {
        const unsigned short* qp = qg + base + (size_t)qrow * NH + 8*g;
        qf0 = *reinterpret_cast<const bf16x8*>(qp);
        qf1 = *reinterpret_cast<const bf16x8*>(qp + 32);
    }

    f32x4 ot[4];
    #pragma unroll
    for (int i = 0; i < 4; ++i) ot[i] = (f32x4){0.f,0.f,0.f,0.f};
    float m = -INFINITY, lsum = 0.f;

    const int nT  = qt + 1;
    const int qhi = q0 + 16*w + 15;

    // staging thread-layout constants
    const int krow = tid >> 3, kc8 = tid & 7;   // K: rows krow, krow+32
    const int vd = lane, vkq = w;               // V^T: col d=lane, kv-chunk = wave

    bf16x8 kpre0, kpre1;
    unsigned short vpre[16];

    // prologue: issue loads for tile 0
    {
        const unsigned short* kp = kg + base + (size_t)krow * NH + kc8*8;
        kpre0 = *reinterpret_cast<const bf16x8*>(kp);
        kpre1 = *reinterpret_cast<const bf16x8*>(kp + 32 * NH);
        #pragma unroll
        for (int i = 0; i < 16; ++i)
            vpre[i] = vg[base + (size_t)(vkq*16 + i) * NH + vd];
    }

    int cur = 0;
    for (int it = 0; it < nT; ++it) {
        const int s0 = it * KVBLK;
        // write staged regs -> LDS[cur]
        *reinterpret_cast<bf16x8*>(&k_lds[cur][krow][kc8*8])      = kpre0;
        *reinterpret_cast<bf16x8*>(&k_lds[cur][krow+32][kc8*8])   = kpre1;
        *reinterpret_cast<bf16x8*>(&vt_lds[cur][vd][vkq*16])      = *reinterpret_cast<bf16x8*>(&vpre[0]);
        *reinterpret_cast<bf16x8*>(&vt_lds[cur][vd][vkq*16 + 8])  = *reinterpret_cast<bf16x8*>(&vpre[8]);
        __syncthreads();

        // issue loads for tile it+1 (in flight during compute)
        if (it + 1 < nT) {
            const int sn = s0 + KVBLK;
            const unsigned short* kp = kg + base + (size_t)(sn + krow) * NH + kc8*8;
            kpre0 = *reinterpret_cast<const bf16x8*>(kp);
            kpre1 = *reinterpret_cast<const bf16x8*>(kp + 32 * NH);
            #pragma unroll
            for (int i = 0; i < 16; ++i)
                vpre[i] = vg[base + (size_t)(sn + vkq*16 + i) * NH + vd];
        }

        if (s0 <= qhi) {
            // ---- S^T = K · Q^T ----
            f32x4 s[4];
            __builtin_amdgcn_s_setprio(1);
            #pragma unroll
            for (int t = 0; t < 4; ++t) {
                bf16x8 ka = *reinterpret_cast<const bf16x8*>(&k_lds[cur][16*t + l15][8*g]);
                bf16x8 kb = *reinterpret_cast<const bf16x8*>(&k_lds[cur][16*t + l15][8*g + 32]);
                s[t] = __builtin_amdgcn_mfma_f32_16x16x32_bf16(ka, qf0, (f32x4){0.f,0.f,0.f,0.f}, 0, 0, 0);
                s[t] = __builtin_amdgcn_mfma_f32_16x16x32_bf16(kb, qf1, s[t], 0, 0, 0);
            }
            __builtin_amdgcn_s_setprio(0);

            // causal mask: lane holds S^T[kv = s0+16t+4g+r][qrow]
            const int kvb = s0 + 4*g;
            #pragma unroll
            for (int t = 0; t < 4; ++t)
                #pragma unroll
                for (int r = 0; r < 4; ++r)
                    if (kvb + 16*t + r > qrow) s[t][r] = -INFINITY;

            // online softmax (reduce over g-groups: 2 shfls)
            float pm = -INFINITY;
            #pragma unroll
            for (int t = 0; t < 4; ++t)
                #pragma unroll
                for (int r = 0; r < 4; ++r) pm = fmaxf(pm, s[t][r]);
            pm = fmaxf(pm, __shfl_xor(pm, 16));
            pm = fmaxf(pm, __shfl_xor(pm, 32));

            float mn   = fmaxf(m, pm);
            float corr = __expf(m - mn);
            m = mn;

            float ps = 0.f;
            #pragma unroll
            for (int t = 0; t < 4; ++t)
                #pragma unroll
                for (int r = 0; r < 4; ++r) {
                    float pv = __expf(s[t][r] - mn);
                    s[t][r] = pv;
                    ps += pv;
                }

            #pragma unroll
            for (int t = 0; t < 4; ++t) {
                unsigned int w0 = (unsigned int)f2bf(s[t][0]) | ((unsigned int)f2bf(s[t][1]) << 16);
                unsigned int w1 = (unsigned int)f2bf(s[t][2]) | ((unsigned int)f2bf(s[t][3]) << 16);
                *reinterpret_cast<unsigned int*>(&p_lds[w][l15][16*t + 4*g])     = w0;
                *reinterpret_cast<unsigned int*>(&p_lds[w][l15][16*t + 4*g + 2]) = w1;
            }

            ps += __shfl_xor(ps, 16);
            ps += __shfl_xor(ps, 32);
            lsum = lsum * corr + ps;

            #pragma unroll
            for (int dt = 0; dt < 4; ++dt)
                #pragma unroll
                for (int e = 0; e < 4; ++e) ot[dt][e] *= corr;

            // ---- O^T += V^T · P^T ----
            __builtin_amdgcn_s_setprio(1);
            #pragma unroll
            for (int kk = 0; kk < 2; ++kk) {
                bf16x8 pf = *reinterpret_cast<const bf16x8*>(&p_lds[w][l15][8*g + 32*kk]);
                #pragma unroll
                for (int dt = 0; dt < 4; ++dt) {
                    bf16x8 vf = *reinterpret_cast<const bf16x8*>(&vt_lds[cur][16*dt + l15][8*g + 32*kk]);
                    ot[dt] = __builtin_amdgcn_mfma_f32_16x16x32_bf16(vf, pf, ot[dt], 0, 0, 0);
                }
            }
            __builtin_amdgcn_s_setprio(0);
        }
        cur ^= 1;
    }

    const float inv = 1.f / lsum;
    float* orow = out + base + (size_t)qrow * NH;
    #pragma unroll
    for (int dt = 0; dt < 4; ++dt) {
        f32x4 o4;
        #pragma unroll
        for (int r = 0; r < 4; ++r) o4[r] = ot[dt][r] * inv;
        *reinterpret_cast<f32x4*>(&orow[16*dt + 4*g]) = o4;
    }
}

extern "C" void kernel_launch(void* const* d_in, const int* in_sizes, int n_in,
                              void* d_out, int out_size, void* d_ws, size_t ws_size,
                              hipStream_t stream) {
    const float* x  = (const float*)d_in[0];
    const float* Wk = (const float*)d_in[1];
    const float* Wq = (const float*)d_in[2];
    const float* Wv = (const float*)d_in[3];
    float* out = (float*)d_out;

    const size_t n = (size_t)NB * NT * NH;            // 1,048,576
    unsigned short* qb = (unsigned short*)d_ws;       // 2 MB each
    unsigned short* kb = qb + n;
    unsigned short* vb = kb + n;
    unsigned short* Wt = vb + n;                      // 192*512 bf16 = 196 KB

    wconv<<<(192*NC)/256, 256, 0, stream>>>(Wk, Wq, Wv, Wt);
    qkv_gemm<<<(NB*NT)/64, 256, 0, stream>>>(x, Wt, qb, kb, vb);
    attn_fwd<<<NB*(NT/QBLK), 256, 0, stream>>>(qb, kb, vb, out);
}

// Round 4
// 64.935 us; speedup vs baseline: 9.3921x; 1.9064x over previous
//
#include <hip/hip_runtime.h>
#include <hip/hip_bf16.h>
#include <math.h>

#define NB 4
#define NT 4096
#define NC 512
#define NH 64
#define QBLK 64
#define KVBLK 64
#define LDK 72      // padded LDS row stride (bf16 elems) = 144 B
#define MASKV (-1e30f)

typedef __attribute__((ext_vector_type(8))) short bf16x8;
typedef __attribute__((ext_vector_type(4))) float f32x4;

__device__ inline unsigned short f2bf(float f) {
    __hip_bfloat16 h = __float2bfloat16(f);
    return *reinterpret_cast<unsigned short*>(&h);
}

// slots for split-KV partials: chunk = 512 kv; nch(qt) = qt/8+1
// cum(qt) = qt + 4*m*(m-1) + r*m  with m=qt/8, r=qt%8 ; total per batch = 288
__device__ inline int part_slot(int b, int qt, int ch) {
    int m = qt >> 3, r = qt & 7;
    return b * 288 + qt + 4 * m * (m - 1) + r * m + ch;
}

// ---------------- Kernel 0: pack W^T bf16 [192][512], Wq pre-scaled ----------------
__global__ __launch_bounds__(256) void wconv(
    const float* __restrict__ Wk, const float* __restrict__ Wq,
    const float* __restrict__ Wv, unsigned short* __restrict__ Wt)
{
    int idx = blockIdx.x * 256 + threadIdx.x;   // 98304 = 512*192
    int n = idx % 192, c = idx / 192;
    int sel = n >> 6, h = n & 63;
    const float* W = (sel == 0) ? Wq : (sel == 1) ? Wk : Wv;
    float val = W[c * NH + h];
    if (sel == 0) val *= 0.044194173824159216f;  // 1/sqrt(512)
    Wt[n * NC + c] = f2bf(val);
}

// ---------------- Kernel 1: QKV projection as MFMA GEMM (BM=32) ----------------
__global__ __launch_bounds__(256) void qkv_gemm(
    const float* __restrict__ x, const unsigned short* __restrict__ Wt,
    unsigned short* __restrict__ q, unsigned short* __restrict__ k,
    unsigned short* __restrict__ v)
{
    __shared__ unsigned short xa[32][LDK];    // A tile  (4.6 KB)
    __shared__ unsigned short wb[192][LDK];   // B tile (27.6 KB)

    const int tid = threadIdx.x;
    const int w = tid >> 6, lane = tid & 63, l15 = lane & 15, g = lane >> 4;
    const size_t r0 = (size_t)blockIdx.x * 32;

    f32x4 acc[2][3];
    #pragma unroll
    for (int mt = 0; mt < 2; ++mt)
        #pragma unroll
        for (int nt = 0; nt < 3; ++nt) acc[mt][nt] = (f32x4){0.f,0.f,0.f,0.f};

    for (int c0 = 0; c0 < NC; c0 += 64) {
        __syncthreads();
        // stage A: 32x64 fp32 -> bf16 (256 chunks of 8, one per thread)
        {
            int row = tid >> 3, f8 = tid & 7;
            const float* xp = x + (r0 + row) * NC + c0 + f8*8;
            float4 x0 = *reinterpret_cast<const float4*>(xp);
            float4 x1 = *reinterpret_cast<const float4*>(xp + 4);
            bf16x8 a8;
            a8[0]=f2bf(x0.x); a8[1]=f2bf(x0.y); a8[2]=f2bf(x0.z); a8[3]=f2bf(x0.w);
            a8[4]=f2bf(x1.x); a8[5]=f2bf(x1.y); a8[6]=f2bf(x1.z); a8[7]=f2bf(x1.w);
            *reinterpret_cast<bf16x8*>(&xa[row][f8*8]) = a8;
        }
        // stage B: 192x64 bf16
        #pragma unroll
        for (int i = 0; i < 6; ++i) {
            int idx = tid + 256*i;
            int row = idx >> 3, f8 = idx & 7;
            bf16x8 w8 = *reinterpret_cast<const bf16x8*>(Wt + (size_t)row * NC + c0 + f8*8);
            *reinterpret_cast<bf16x8*>(&wb[row][f8*8]) = w8;
        }
        __syncthreads();

        #pragma unroll
        for (int kk = 0; kk < 2; ++kk) {
            bf16x8 a[2], bfr[3];
            #pragma unroll
            for (int mt = 0; mt < 2; ++mt)
                a[mt] = *reinterpret_cast<const bf16x8*>(&xa[16*mt + l15][32*kk + 8*g]);
            #pragma unroll
            for (int nt = 0; nt < 3; ++nt)
                bfr[nt] = *reinterpret_cast<const bf16x8*>(&wb[48*w + 16*nt + l15][32*kk + 8*g]);
            __builtin_amdgcn_s_setprio(1);
            #pragma unroll
            for (int mt = 0; mt < 2; ++mt)
                #pragma unroll
                for (int nt = 0; nt < 3; ++nt)
                    acc[mt][nt] = __builtin_amdgcn_mfma_f32_16x16x32_bf16(a[mt], bfr[nt], acc[mt][nt], 0, 0, 0);
            __builtin_amdgcn_s_setprio(0);
        }
    }

    #pragma unroll
    for (int mt = 0; mt < 2; ++mt)
        #pragma unroll
        for (int nt = 0; nt < 3; ++nt) {
            int ncol = 48*w + 16*nt + l15;
            int sel = ncol >> 6, h = ncol & 63;
            unsigned short* dst = (sel == 0) ? q : (sel == 1) ? k : v;
            #pragma unroll
            for (int r = 0; r < 4; ++r)
                dst[(r0 + 16*mt + 4*g + r) * NH + h] = f2bf(acc[mt][nt][r]);
        }
}

// ---------------- Kernel 2: split-KV MFMA flash attention (pass 1) ----------------
// grid (64 qt, 8 ch, 4 b); qt reversed so heavy blocks dispatch first.
// Block covers kv chunk [512*ch, min(512*(ch+1), (qt+1)*64)) for q-tile qt.
// nch==1 (qt<8): write final output. Else: write unnormalized o + (m,l) partials.
__global__ __launch_bounds__(256) void attn_part(
    const unsigned short* __restrict__ qg,
    const unsigned short* __restrict__ kg,
    const unsigned short* __restrict__ vg,
    float* __restrict__ out,
    float* __restrict__ O_part,
    float* __restrict__ ML_part)
{
    const int qt = 63 - blockIdx.x;
    const int ch = blockIdx.y;
    if (8*ch > qt) return;                      // inactive block
    const int b  = blockIdx.z;
    const int nch = (qt >> 3) + 1;

    __shared__ unsigned short k_lds[2][KVBLK][LDK];
    __shared__ unsigned short vt_lds[2][NH][LDK];
    __shared__ unsigned short p_lds[4][16][LDK];

    const int tid  = threadIdx.x;
    const int w    = tid >> 6;
    const int lane = tid & 63;
    const int l15  = lane & 15;
    const int g    = lane >> 4;

    const int q0 = qt * QBLK;
    const size_t base = (size_t)b * NT * NH;
    const int qrow  = q0 + 16*w + l15;
    const int wrow0 = q0 + 16*w;
    const int qhi   = wrow0 + 15;

    bf16x8 qf0, qf1;
    {
        const unsigned short* qp = qg + base + (size_t)qrow * NH + 8*g;
        qf0 = *reinterpret_cast<const bf16x8*>(qp);
        qf1 = *reinterpret_cast<const bf16x8*>(qp + 32);
    }

    f32x4 ot[4];
    #pragma unroll
    for (int i = 0; i < 4; ++i) ot[i] = (f32x4){0.f,0.f,0.f,0.f};
    float m = MASKV, lsum = 0.f;

    const int tBeg = 8 * ch;
    const int tEnd = min(8 * (ch + 1), qt + 1);   // exclusive

    const int krow = tid >> 3, kc8 = tid & 7;
    const int vd = lane, vkq = w;

    bf16x8 kpre0, kpre1;
    unsigned short vpre[16];

    // prologue: issue loads for first tile of the chunk
    {
        const int s0 = tBeg * KVBLK;
        const unsigned short* kp = kg + base + (size_t)(s0 + krow) * NH + kc8*8;
        kpre0 = *reinterpret_cast<const bf16x8*>(kp);
        kpre1 = *reinterpret_cast<const bf16x8*>(kp + 32 * NH);
        #pragma unroll
        for (int i = 0; i < 16; ++i)
            vpre[i] = vg[base + (size_t)(s0 + vkq*16 + i) * NH + vd];
    }

    int cur = 0;
    for (int it = tBeg; it < tEnd; ++it) {
        const int s0 = it * KVBLK;
        *reinterpret_cast<bf16x8*>(&k_lds[cur][krow][kc8*8])      = kpre0;
        *reinterpret_cast<bf16x8*>(&k_lds[cur][krow+32][kc8*8])   = kpre1;
        *reinterpret_cast<bf16x8*>(&vt_lds[cur][vd][vkq*16])      = *reinterpret_cast<bf16x8*>(&vpre[0]);
        *reinterpret_cast<bf16x8*>(&vt_lds[cur][vd][vkq*16 + 8])  = *reinterpret_cast<bf16x8*>(&vpre[8]);
        __syncthreads();

        if (it + 1 < tEnd) {   // issue loads for next tile (in flight during compute)
            const int sn = s0 + KVBLK;
            const unsigned short* kp = kg + base + (size_t)(sn + krow) * NH + kc8*8;
            kpre0 = *reinterpret_cast<const bf16x8*>(kp);
            kpre1 = *reinterpret_cast<const bf16x8*>(kp + 32 * NH);
            #pragma unroll
            for (int i = 0; i < 16; ++i)
                vpre[i] = vg[base + (size_t)(sn + vkq*16 + i) * NH + vd];
        }

        if (s0 <= qhi) {
            // ---- S^T = K · Q^T ----
            f32x4 s[4];
            __builtin_amdgcn_s_setprio(1);
            #pragma unroll
            for (int t = 0; t < 4; ++t) {
                bf16x8 ka = *reinterpret_cast<const bf16x8*>(&k_lds[cur][16*t + l15][8*g]);
                bf16x8 kb = *reinterpret_cast<const bf16x8*>(&k_lds[cur][16*t + l15][8*g + 32]);
                s[t] = __builtin_amdgcn_mfma_f32_16x16x32_bf16(ka, qf0, (f32x4){0.f,0.f,0.f,0.f}, 0, 0, 0);
                s[t] = __builtin_amdgcn_mfma_f32_16x16x32_bf16(kb, qf1, s[t], 0, 0, 0);
            }
            __builtin_amdgcn_s_setprio(0);

            // causal mask only on diagonal-touching tiles (wave-uniform branch)
            if (s0 + 63 > wrow0) {
                const int kvb = s0 + 4*g;
                #pragma unroll
                for (int t = 0; t < 4; ++t)
                    #pragma unroll
                    for (int r = 0; r < 4; ++r)
                        if (kvb + 16*t + r > qrow) s[t][r] = MASKV;
            }

            float pm = MASKV;
            #pragma unroll
            for (int t = 0; t < 4; ++t)
                #pragma unroll
                for (int r = 0; r < 4; ++r) pm = fmaxf(pm, s[t][r]);
            pm = fmaxf(pm, __shfl_xor(pm, 16));
            pm = fmaxf(pm, __shfl_xor(pm, 32));

            // defer-max (T13): rescale only when max grew by > 8
            if (!__all(pm <= m + 8.f)) {
                float mn   = fmaxf(m, pm);
                float corr = __expf(m - mn);
                lsum *= corr;
                #pragma unroll
                for (int dt = 0; dt < 4; ++dt)
                    #pragma unroll
                    for (int e = 0; e < 4; ++e) ot[dt][e] *= corr;
                m = mn;
            }

            float ps = 0.f;
            #pragma unroll
            for (int t = 0; t < 4; ++t)
                #pragma unroll
                for (int r = 0; r < 4; ++r) {
                    float pv = __expf(s[t][r] - m);
                    s[t][r] = pv;
                    ps += pv;
                }

            #pragma unroll
            for (int t = 0; t < 4; ++t) {
                unsigned int w0 = (unsigned int)f2bf(s[t][0]) | ((unsigned int)f2bf(s[t][1]) << 16);
                unsigned int w1 = (unsigned int)f2bf(s[t][2]) | ((unsigned int)f2bf(s[t][3]) << 16);
                *reinterpret_cast<unsigned int*>(&p_lds[w][l15][16*t + 4*g])     = w0;
                *reinterpret_cast<unsigned int*>(&p_lds[w][l15][16*t + 4*g + 2]) = w1;
            }

            ps += __shfl_xor(ps, 16);
            ps += __shfl_xor(ps, 32);
            lsum += ps;

            // ---- O^T += V^T · P^T ----
            __builtin_amdgcn_s_setprio(1);
            #pragma unroll
            for (int kk = 0; kk < 2; ++kk) {
                bf16x8 pf = *reinterpret_cast<const bf16x8*>(&p_lds[w][l15][8*g + 32*kk]);
                #pragma unroll
                for (int dt = 0; dt < 4; ++dt) {
                    bf16x8 vf = *reinterpret_cast<const bf16x8*>(&vt_lds[cur][16*dt + l15][8*g + 32*kk]);
                    ot[dt] = __builtin_amdgcn_mfma_f32_16x16x32_bf16(vf, pf, ot[dt], 0, 0, 0);
                }
            }
            __builtin_amdgcn_s_setprio(0);
        }
        cur ^= 1;
    }

    if (nch == 1) {
        const float inv = 1.f / lsum;
        float* orow = out + base + (size_t)qrow * NH;
        #pragma unroll
        for (int dt = 0; dt < 4; ++dt) {
            f32x4 o4;
            #pragma unroll
            for (int r = 0; r < 4; ++r) o4[r] = ot[dt][r] * inv;
            *reinterpret_cast<f32x4*>(&orow[16*dt + 4*g]) = o4;
        }
    } else {
        const int slot = part_slot(b, qt, ch);
        float* op = O_part + (size_t)slot * (QBLK*NH) + (size_t)(16*w + l15) * NH;
        #pragma unroll
        for (int dt = 0; dt < 4; ++dt)
            *reinterpret_cast<f32x4*>(&op[16*dt + 4*g]) = ot[dt];
        if (g == 0) {
            float2 ml = make_float2(m, lsum);
            *reinterpret_cast<float2*>(&ML_part[(size_t)slot * 128 + 2*(16*w + l15)]) = ml;
        }
    }
}

// ---------------- Kernel 3: merge split-KV partials ----------------
// grid (56 qt-tiles [qt>=8], 4 b); 256 threads: 4 threads per q-row, 16 d each.
__global__ __launch_bounds__(256) void attn_merge(
    const float* __restrict__ O_part,
    const float* __restrict__ ML_part,
    float* __restrict__ out)
{
    const int qt = 8 + blockIdx.x;
    const int b  = blockIdx.y;
    const int nch = (qt >> 3) + 1;
    const int slot0 = part_slot(b, qt, 0);
    const int row = threadIdx.x >> 2;
    const int dq  = (threadIdx.x & 3) * 16;

    float M = MASKV;
    #pragma unroll 2
    for (int c = 0; c < nch; ++c)
        M = fmaxf(M, ML_part[(size_t)(slot0 + c) * 128 + 2*row]);

    float L = 0.f;
    float acc[16];
    #pragma unroll
    for (int j = 0; j < 16; ++j) acc[j] = 0.f;

    for (int c = 0; c < nch; ++c) {
        const float* mlp = &ML_part[(size_t)(slot0 + c) * 128 + 2*row];
        float mc = mlp[0], lc = mlp[1];
        float wgt = __expf(mc - M);
        L += wgt * lc;
        const float* op = O_part + (size_t)(slot0 + c) * (QBLK*NH) + (size_t)row * NH + dq;
        #pragma unroll
        for (int j4 = 0; j4 < 4; ++j4) {
            float4 o4 = *reinterpret_cast<const float4*>(op + 4*j4);
            acc[4*j4+0] = fmaf(wgt, o4.x, acc[4*j4+0]);
            acc[4*j4+1] = fmaf(wgt, o4.y, acc[4*j4+1]);
            acc[4*j4+2] = fmaf(wgt, o4.z, acc[4*j4+2]);
            acc[4*j4+3] = fmaf(wgt, o4.w, acc[4*j4+3]);
        }
    }

    const float inv = 1.f / L;
    float* orow = out + (size_t)b * NT * NH + (size_t)(qt * QBLK + row) * NH + dq;
    #pragma unroll
    for (int j4 = 0; j4 < 4; ++j4) {
        float4 o4;
        o4.x = acc[4*j4+0] * inv;
        o4.y = acc[4*j4+1] * inv;
        o4.z = acc[4*j4+2] * inv;
        o4.w = acc[4*j4+3] * inv;
        *reinterpret_cast<float4*>(orow + 4*j4) = o4;
    }
}

extern "C" void kernel_launch(void* const* d_in, const int* in_sizes, int n_in,
                              void* d_out, int out_size, void* d_ws, size_t ws_size,
                              hipStream_t stream) {
    const float* x  = (const float*)d_in[0];
    const float* Wk = (const float*)d_in[1];
    const float* Wq = (const float*)d_in[2];
    const float* Wv = (const float*)d_in[3];
    float* out = (float*)d_out;

    const size_t n = (size_t)NB * NT * NH;            // 1,048,576
    unsigned short* qb = (unsigned short*)d_ws;       // 2 MB each
    unsigned short* kb = qb + n;
    unsigned short* vb = kb + n;
    unsigned short* Wt = vb + n;                      // 196 KB
    float* O_part  = (float*)(Wt + 192 * NC);         // 1152 slots * 16 KB = 18.9 MB
    float* ML_part = O_part + (size_t)1152 * QBLK * NH;  // 1152 * 512 B

    wconv<<<(192*NC)/256, 256, 0, stream>>>(Wk, Wq, Wv, Wt);
    qkv_gemm<<<(NB*NT)/32, 256, 0, stream>>>(x, Wt, qb, kb, vb);

    dim3 pgrid(64, 8, NB);
    attn_part<<<pgrid, 256, 0, stream>>>(qb, kb, vb, out, O_part, ML_part);
    dim3 mgrid(56, NB);
    attn_merge<<<mgrid, 256, 0, stream>>>(O_part, ML_part, out);
}